// Round 17
// baseline (231.746 us; speedup 1.0000x reference)
//
#include <hip/hip_runtime.h>
#include <hip/hip_bf16.h>
#include <hip/hip_fp16.h>

#define F 32
#define S 16

typedef short v8s __attribute__((ext_vector_type(8)));
typedef float v4f __attribute__((ext_vector_type(4)));

__device__ __forceinline__ unsigned short f2bf(float f) {
    __hip_bfloat16 h = __float2bfloat16(f);  // RNE
    return *(unsigned short*)&h;
}
__device__ __forceinline__ unsigned pack2(float a, float b) {
    return (unsigned)f2bf(a) | ((unsigned)f2bf(b) << 16);
}
static inline size_t align256(size_t b) { return (b + 255) & ~(size_t)255; }

// ---------------------------------------------------------------------------
// Weight prep per layer (R14-verified fragment order):
//  Wfrag[fi][lane][j]: fi = ck*2+half, o = half*16+(lane&15),
//  k = ck*32+(lane>>4)*8+j; s<16 -> fgn_w[s,f*32+o]; s==16 -> fgn_b.
//  Rt[o][f] (32x32): root[f*32+o].
// ---------------------------------------------------------------------------
__global__ __launch_bounds__(256) void convert_w2(
    const float* __restrict__ w1, const float* __restrict__ b1, const float* __restrict__ r1,
    const float* __restrict__ w2, const float* __restrict__ b2, const float* __restrict__ r2,
    unsigned short* __restrict__ Wf1, unsigned short* __restrict__ Wf2,
    unsigned short* __restrict__ Rt1, unsigned short* __restrict__ Rt2)
{
    const int PER = 34 * 512 + 32 * 32;
    int tid = blockIdx.x * blockDim.x + threadIdx.x;
    if (tid >= 2 * PER) return;
    const int layer = tid / PER;
    const int rem   = tid % PER;
    const float* w = layer ? w2 : w1;
    const float* b = layer ? b2 : b1;
    const float* r = layer ? r2 : r1;
    if (rem < 34 * 512) {
        const int fi   = rem >> 9;
        const int rr   = rem & 511;
        const int lane = rr >> 3;
        const int j    = rr & 7;
        const int half = fi & 1;
        const int ck   = fi >> 1;
        const int o    = (half << 4) | (lane & 15);
        const int k    = ck * 32 + (lane >> 4) * 8 + j;
        const int s    = k >> 5, f = k & 31;
        const float v  = (s < S) ? w[s * (F * F) + f * F + o] : b[f * F + o];
        (layer ? Wf2 : Wf1)[rem] = f2bf(v);
    } else {
        const int q = rem - 34 * 512;
        const int o = q >> 5, f = q & 31;
        (layer ? Rt2 : Rt1)[o * F + f] = f2bf(r[f * F + o]);
    }
}

// ---------------------------------------------------------------------------
// edge_msg: R14's LDS-fragment-W compute body (the verified W fix) with
// R10's pk-fp16 atomic scatter (verified mapping). NO sort, NO msg buffer.
// D = mfma(W_frag, Z_frag): col = edge (lid), row = o; lane holds
// o = quad*4..+3 (acc0) and 16+quad*4..+3 (acc1) of its own edge.
// ---------------------------------------------------------------------------
__global__ __launch_bounds__(256) void edge_msg(
    const float* __restrict__ xin,          // (N,F) fp32 node feats
    const float* __restrict__ ef,           // (E,S)
    const int* __restrict__ src,
    const int* __restrict__ dst,
    const unsigned short* __restrict__ Wf,  // (34*512) bf16 fragment order
    __half2* __restrict__ agg,              // (N,16) fp16 pairs, pre-zeroed
    int E)
{
    __shared__ v8s Wl[34 * 64];             // 34816 B
    const int tid  = threadIdx.x;
    const int w    = tid >> 6;
    const int lane = tid & 63;
    const int lid  = lane & 15;
    const int quad = lane >> 4;

    // stage W -> LDS (coalesced uint4)
    {
        const uint4* s = (const uint4*)Wf;
        uint4* d = (uint4*)Wl;
        #pragma unroll
        for (int i = 0; i < 9; ++i) {
            const int idx = tid + 256 * i;
            if (idx < 2176) d[idx] = s[idx];
        }
    }
    __syncthreads();

    const int nTiles = (E + 15) >> 4;
    for (int tile = blockIdx.x * 4 + w; tile < nTiles; tile += gridDim.x * 4) {
        const int  slot = tile * 16 + lid;
        const bool live = (slot < E);
        const int  e    = live ? slot : 0;
        const int  sn   = src[e];
        const int  dn   = dst[e];
        const float4* xp = (const float4*)(xin + (size_t)sn * F + quad * 8);
        const float4 xv0 = xp[0], xv1 = xp[1];
        const float4* efv = (const float4*)(ef + (size_t)e * S);
        const float4 c0 = efv[0], c1 = efv[1], c2 = efv[2], c3 = efv[3];
        const float cs[S] = {c0.x, c0.y, c0.z, c0.w, c1.x, c1.y, c1.z, c1.w,
                             c2.x, c2.y, c2.z, c2.w, c3.x, c3.y, c3.z, c3.w};

        v4f acc0 = {0.f, 0.f, 0.f, 0.f};
        v4f acc1 = {0.f, 0.f, 0.f, 0.f};

        #pragma unroll
        for (int ck = 0; ck < S; ++ck) {
            const float sc = cs[ck];
            union { v8s s8; uint4 u4; } fr;
            fr.u4.x = pack2(sc * xv0.x, sc * xv0.y);
            fr.u4.y = pack2(sc * xv0.z, sc * xv0.w);
            fr.u4.z = pack2(sc * xv1.x, sc * xv1.y);
            fr.u4.w = pack2(sc * xv1.z, sc * xv1.w);
            acc0 = __builtin_amdgcn_mfma_f32_16x16x32_bf16(Wl[(2 * ck) * 64 + lane],     fr.s8, acc0, 0, 0, 0);
            acc1 = __builtin_amdgcn_mfma_f32_16x16x32_bf16(Wl[(2 * ck + 1) * 64 + lane], fr.s8, acc1, 0, 0, 0);
        }
        {   // fgn bias slice: Z = x itself
            union { v8s s8; uint4 u4; } fr;
            fr.u4.x = pack2(xv0.x, xv0.y);
            fr.u4.y = pack2(xv0.z, xv0.w);
            fr.u4.z = pack2(xv1.x, xv1.y);
            fr.u4.w = pack2(xv1.z, xv1.w);
            acc0 = __builtin_amdgcn_mfma_f32_16x16x32_bf16(Wl[32 * 64 + lane], fr.s8, acc0, 0, 0, 0);
            acc1 = __builtin_amdgcn_mfma_f32_16x16x32_bf16(Wl[33 * 64 + lane], fr.s8, acc1, 0, 0, 0);
        }

        if (live) {
            __half2* ap = agg + (size_t)dn * 16;
            unsafeAtomicAdd(ap + quad * 2,         __floats2half2_rn(acc0[0], acc0[1]));
            unsafeAtomicAdd(ap + quad * 2 + 1,     __floats2half2_rn(acc0[2], acc0[3]));
            unsafeAtomicAdd(ap + 8 + quad * 2,     __floats2half2_rn(acc1[0], acc1[1]));
            unsafeAtomicAdd(ap + 8 + quad * 2 + 1, __floats2half2_rn(acc1[2], acc1[3]));
        }
    }
}

// ---------------------------------------------------------------------------
// root_fuse (R10-verified): h[n,o] = relu(agg[n,o] + sum_f in[n,f]*root[f,o] + bias[o])
// ---------------------------------------------------------------------------
__global__ __launch_bounds__(256) void root_fuse(
    const float* __restrict__ in,          // (N,F) fp32
    const __half2* __restrict__ agg,       // (N,16)
    const unsigned short* __restrict__ Rt, // (32,32) bf16 [o][f]
    const float* __restrict__ bias,
    float* __restrict__ h,                 // (N,F) fp32 out
    int N)
{
    __shared__ unsigned short As[64 * F];  // 4096 B, fragment order
    const int tid  = threadIdx.x;
    const int n0   = blockIdx.x * 64;
    const int w    = tid >> 6;
    const int lane = tid & 63;
    const int lid  = lane & 15;
    const int quad = lane >> 4;

    {   // stage 64-node bf16 tile in fragment order
        const int nl = tid >> 2;
        const int kq = tid & 3;
        int n = n0 + nl; if (n > N - 1) n = N - 1;
        const float4* xp = (const float4*)(in + (size_t)n * F + kq * 8);
        float4 v0 = xp[0], v1 = xp[1];
        uint4 pk;
        pk.x = pack2(v0.x, v0.y);
        pk.y = pack2(v0.z, v0.w);
        pk.z = pack2(v1.x, v1.y);
        pk.w = pack2(v1.z, v1.w);
        const int slot = ((nl >> 4) * 4 + kq) * 16 + (nl & 15);
        *(uint4*)(As + slot * 8) = pk;
    }
    __syncthreads();

    const int jt  = w & 1;
    const int ns0 = (w >> 1) * 2;
    const v8s rf = *(const v8s*)(Rt + (size_t)(jt * 16 + lid) * F + quad * 8);
    const int o0 = jt * 16 + quad * 4;
    const float4 bs = *(const float4*)(bias + o0);

    #pragma unroll
    for (int i = 0; i < 2; ++i) {
        const int ns = ns0 + i;
        const v8s af = *(const v8s*)(As + (((ns * 4 + quad) * 16) + lid) * 8);
        v4f d = {0.f, 0.f, 0.f, 0.f};
        d = __builtin_amdgcn_mfma_f32_16x16x32_bf16(rf, af, d, 0, 0, 0);
        const int n = n0 + ns * 16 + lid;
        if (n < N) {
            const uint2 au = *(const uint2*)(agg + (size_t)n * 16 + o0 / 2);
            const float2 a01 = __half22float2(*(const __half2*)&au.x);
            const float2 a23 = __half22float2(*(const __half2*)&au.y);
            float4 hv;
            hv.x = fmaxf(d[0] + a01.x + bs.x, 0.f);
            hv.y = fmaxf(d[1] + a01.y + bs.y, 0.f);
            hv.z = fmaxf(d[2] + a23.x + bs.z, 0.f);
            hv.w = fmaxf(d[3] + a23.y + bs.w, 0.f);
            *(float4*)(h + (size_t)n * F + o0) = hv;
        }
    }
}

// ---------------------------------------------------------------------------
// pool_final (R16-verified): pool + dense fused via atomic-ticket last block.
// ---------------------------------------------------------------------------
__global__ __launch_bounds__(256) void pool_final(
    const float* __restrict__ h, float* __restrict__ pooled, int* __restrict__ counter,
    const float* __restrict__ dw, const float* __restrict__ db,
    float* __restrict__ out, int N, int nBlocks)
{
    const int c = threadIdx.x & (F - 1);
    float p = 0.0f;
    for (int n = blockIdx.x * 8 + (threadIdx.x >> 5); n < N; n += gridDim.x * 8)
        p += h[(size_t)n * F + c];
    __shared__ float red[256];
    red[threadIdx.x] = p;
    __syncthreads();
    for (int off = 128; off >= F; off >>= 1) {
        if (threadIdx.x < off) red[threadIdx.x] += red[threadIdx.x + off];
        __syncthreads();
    }
    if (threadIdx.x < F) atomicAdd(&pooled[threadIdx.x], red[threadIdx.x]);
    __threadfence();
    __shared__ int lastFlag;
    if (threadIdx.x == 0) {
        const int t = atomicAdd(counter, 1);
        lastFlag = (t == nBlocks - 1) ? 1 : 0;
    }
    __syncthreads();
    if (lastFlag && threadIdx.x < 64) {
        const int o = threadIdx.x;
        float v = 0.f;
        if (o < F) v = atomicAdd(&pooled[o], 0.0f) * dw[o];  // atomic read (coherent)
        #pragma unroll
        for (int off = 32; off > 0; off >>= 1) v += __shfl_down(v, off, 64);
        if (o == 0) out[0] = v + db[0];
    }
}

// ---------------------------------------------------------------------------
// Last-resort fallback (tiny ws): round-1 implementation.
// ---------------------------------------------------------------------------
__global__ __launch_bounds__(256, 2) void ecc_edge_slow(
    const float* __restrict__ x, const float* __restrict__ ef,
    const int* __restrict__ src, const int* __restrict__ dst,
    const float* __restrict__ W, const float* __restrict__ B,
    float* __restrict__ agg, int E)
{
    const int tid = blockIdx.x * blockDim.x + threadIdx.x;
    const bool live = (tid < E);
    const int e = live ? tid : (E - 1);
    const int sn = src[e], dn = dst[e];
    float xr[F];
    const float4* xp = (const float4*)(x + (size_t)sn * F);
    #pragma unroll
    for (int i = 0; i < F / 4; ++i) {
        float4 v = xp[i];
        xr[4*i+0] = v.x; xr[4*i+1] = v.y; xr[4*i+2] = v.z; xr[4*i+3] = v.w;
    }
    float acc[F];
    #pragma unroll
    for (int o = 0; o < F; ++o) acc[o] = 0.0f;
    const float* erow = ef + (size_t)e * S;
    for (int s = 0; s < S; ++s) {
        const float es = erow[s];
        const float* Ws = W + s * (F * F);
        #pragma unroll
        for (int f = 0; f < F; ++f) {
            const float z = es * xr[f];
            #pragma unroll
            for (int o = 0; o < F; ++o) acc[o] = fmaf(z, Ws[f * F + o], acc[o]);
        }
    }
    #pragma unroll
    for (int f = 0; f < F; ++f) {
        const float xf = xr[f];
        #pragma unroll
        for (int o = 0; o < F; ++o) acc[o] = fmaf(xf, B[f * F + o], acc[o]);
    }
    if (live) {
        float* ap = agg + (size_t)dn * F;
        #pragma unroll
        for (int o = 0; o < F; ++o) atomicAdd(ap + o, acc[o]);
    }
}

__global__ __launch_bounds__(256) void ecc_node_slow(
    const float* __restrict__ xin, const float* __restrict__ root,
    const float* __restrict__ bias, float* __restrict__ h, int N)
{
    int t = blockIdx.x * blockDim.x + threadIdx.x;
    if (t >= N * F) return;
    const int n = t >> 5, o = t & (F - 1);
    const float* xrow = xin + (size_t)n * F;
    float v = h[t] + bias[o];
    #pragma unroll
    for (int f = 0; f < F; ++f) v = fmaf(xrow[f], root[f * F + o], v);
    h[t] = fmaxf(v, 0.0f);
}

__global__ __launch_bounds__(256) void pool_kernel(
    const float* __restrict__ h, float* __restrict__ pooled, int N)
{
    const int c = threadIdx.x & (F - 1);
    float p = 0.0f;
    for (int n = blockIdx.x * 8 + (threadIdx.x >> 5); n < N; n += gridDim.x * 8)
        p += h[(size_t)n * F + c];
    __shared__ float red[256];
    red[threadIdx.x] = p;
    __syncthreads();
    for (int off = 128; off >= F; off >>= 1) {
        if (threadIdx.x < off) red[threadIdx.x] += red[threadIdx.x + off];
        __syncthreads();
    }
    if (threadIdx.x < F) atomicAdd(&pooled[threadIdx.x], red[threadIdx.x]);
}

__global__ void final_kernel(
    const float* __restrict__ pooled, const float* __restrict__ dw,
    const float* __restrict__ db, float* __restrict__ out)
{
    const int o = threadIdx.x;
    float v = (o < F) ? pooled[o] * dw[o] : 0.0f;
    #pragma unroll
    for (int off = 32; off > 0; off >>= 1) v += __shfl_down(v, off, 64);
    if (o == 0) out[0] = v + db[0];
}

// ---------------------------------------------------------------------------
extern "C" void kernel_launch(void* const* d_in, const int* in_sizes, int n_in,
                              void* d_out, int out_size, void* d_ws, size_t ws_size,
                              hipStream_t stream) {
    const float* x      = (const float*)d_in[0];
    const float* efeat  = (const float*)d_in[1];
    const int*   src    = (const int*)d_in[2];
    const int*   dst    = (const int*)d_in[3];
    const float* fgn_w1 = (const float*)d_in[4];
    const float* fgn_b1 = (const float*)d_in[5];
    const float* root1  = (const float*)d_in[6];
    const float* bias1  = (const float*)d_in[7];
    const float* fgn_w2 = (const float*)d_in[8];
    const float* fgn_b2 = (const float*)d_in[9];
    const float* root2  = (const float*)d_in[10];
    const float* bias2  = (const float*)d_in[11];
    const float* dense_w = (const float*)d_in[12];
    const float* dense_b = (const float*)d_in[13];

    const int N = in_sizes[0] / F;
    const int E = in_sizes[2];

    const size_t pooledB = 256;                    // 32 floats + counter + pad
    const size_t aggB    = align256((size_t)N * 16 * 4);  // fp16x2 agg, 3.2 MB
    const size_t hB      = (size_t)N * F * 4;
    const size_t wfB     = align256((size_t)34 * 512 * 2);
    const size_t rtB     = align256((size_t)32 * 32 * 2);

    // layout: pooled | agg1 | agg2 | h1 | h2 | Wf1 | Wf2 | Rt1 | Rt2
    const size_t offA1 = pooledB;
    const size_t offA2 = offA1 + aggB;
    const size_t offH1 = offA2 + aggB;
    const size_t offH2 = offH1 + hB;
    const size_t offW1 = offH2 + hB;
    const size_t offW2 = offW1 + wfB;
    const size_t offR1 = offW2 + wfB;
    const size_t offR2 = offR1 + rtB;
    const size_t need  = offR2 + rtB;

    const int eB         = (E + 255) / 256;
    const int nodeBlocks = (N * F + 255) / 256;

    if (ws_size >= need) {
        float* pooled  = (float*)d_ws;
        int*   counter = (int*)((char*)d_ws + F * sizeof(float));
        __half2* agg1  = (__half2*)((char*)d_ws + offA1);
        __half2* agg2  = (__half2*)((char*)d_ws + offA2);
        float* h1      = (float*)((char*)d_ws + offH1);
        float* h2      = (float*)((char*)d_ws + offH2);
        unsigned short* Wf1 = (unsigned short*)((char*)d_ws + offW1);
        unsigned short* Wf2 = (unsigned short*)((char*)d_ws + offW2);
        unsigned short* Rt1 = (unsigned short*)((char*)d_ws + offR1);
        unsigned short* Rt2 = (unsigned short*)((char*)d_ws + offR2);

        // zero pooled + counter + agg1 + agg2 (contiguous prefix)
        hipMemsetAsync(d_ws, 0, pooledB + 2 * aggB, stream);

        convert_w2<<<(2 * 18432 + 255) / 256, 256, 0, stream>>>(
            fgn_w1, fgn_b1, root1, fgn_w2, fgn_b2, root2, Wf1, Wf2, Rt1, Rt2);

        const int nTiles = (E + 15) / 16;
        int edgeBlocks = (nTiles + 3) / 4;
        if (edgeBlocks > 1024) edgeBlocks = 1024;
        const int rootBlocks = (N + 63) / 64;

        // ---- layer 1 ----
        edge_msg <<<edgeBlocks, 256, 0, stream>>>(x, efeat, src, dst, Wf1, agg1, E);
        root_fuse<<<rootBlocks, 256, 0, stream>>>(x, agg1, Rt1, bias1, h1, N);

        // ---- layer 2 ----
        edge_msg <<<edgeBlocks, 256, 0, stream>>>(h1, efeat, src, dst, Wf2, agg2, E);
        root_fuse<<<rootBlocks, 256, 0, stream>>>(h1, agg2, Rt2, bias2, h2, N);

        // ---- pool + dense ----
        pool_final<<<512, 256, 0, stream>>>(h2, pooled, counter, dense_w, dense_b,
                                            (float*)d_out, N, 512);
    } else {
        float* agg1   = (float*)d_ws;
        float* agg2   = agg1 + (size_t)N * F;
        float* pooled = agg2 + (size_t)N * F;
        hipMemsetAsync(d_ws, 0, (2 * (size_t)N * F + F) * sizeof(float), stream);
        ecc_edge_slow<<<eB, 256, 0, stream>>>(x, efeat, src, dst, fgn_w1, fgn_b1, agg1, E);
        ecc_node_slow<<<nodeBlocks, 256, 0, stream>>>(x, root1, bias1, agg1, N);
        ecc_edge_slow<<<eB, 256, 0, stream>>>(agg1, efeat, src, dst, fgn_w2, fgn_b2, agg2, E);
        ecc_node_slow<<<nodeBlocks, 256, 0, stream>>>(agg1, root2, bias2, agg2, N);
        pool_kernel <<<512, 256, 0, stream>>>(agg2, pooled, N);
        final_kernel<<<1, 64, 0, stream>>>(pooled, dense_w, dense_b, (float*)d_out);
    }
}

// Round 18
// 199.799 us; speedup vs baseline: 1.1599x; 1.1599x over previous
//
#include <hip/hip_runtime.h>
#include <hip/hip_bf16.h>

#define F 32
#define S 16

typedef short v8s __attribute__((ext_vector_type(8)));
typedef float v4f __attribute__((ext_vector_type(4)));

__device__ __forceinline__ float bf_lo(unsigned u) { return __uint_as_float(u << 16); }
__device__ __forceinline__ float bf_hi(unsigned u) { return __uint_as_float(u & 0xffff0000u); }
__device__ __forceinline__ unsigned short f2bf(float f) {
    __hip_bfloat16 h = __float2bfloat16(f);  // RNE
    return *(unsigned short*)&h;
}
__device__ __forceinline__ unsigned pack2(float a, float b) {
    __hip_bfloat162 h2 = __float22bfloat162_rn(make_float2(a, b));  // v_cvt_pk_bf16_f32
    return *(unsigned*)&h2;
}
static inline size_t align256(size_t b) { return (b + 255) & ~(size_t)255; }

// ---------------------------------------------------------------------------
// Weight prep per layer, PRE-PACKED IN MFMA FRAGMENT ORDER (R14-verified).
// ---------------------------------------------------------------------------
__global__ __launch_bounds__(256) void convert_w2(
    const float* __restrict__ w1, const float* __restrict__ b1, const float* __restrict__ r1,
    const float* __restrict__ w2, const float* __restrict__ b2, const float* __restrict__ r2,
    unsigned short* __restrict__ Wf1, unsigned short* __restrict__ Wf2,
    unsigned short* __restrict__ Rt1, unsigned short* __restrict__ Rt2)
{
    const int PER = 34 * 512 + 32 * 32;
    int tid = blockIdx.x * blockDim.x + threadIdx.x;
    if (tid >= 2 * PER) return;
    const int layer = tid / PER;
    const int rem   = tid % PER;
    const float* w = layer ? w2 : w1;
    const float* b = layer ? b2 : b1;
    const float* r = layer ? r2 : r1;
    if (rem < 34 * 512) {
        const int fi   = rem >> 9;
        const int rr   = rem & 511;
        const int lane = rr >> 3;
        const int j    = rr & 7;
        const int half = fi & 1;
        const int ck   = fi >> 1;
        const int o    = (half << 4) | (lane & 15);
        const int k    = ck * 32 + (lane >> 4) * 8 + j;
        const int s    = k >> 5, f = k & 31;
        const float v  = (s < S) ? w[s * (F * F) + f * F + o] : b[f * F + o];
        (layer ? Wf2 : Wf1)[rem] = f2bf(v);
    } else {
        const int q = rem - 34 * 512;
        const int o = q >> 5, f = q & 31;
        (layer ? Rt2 : Rt1)[o * F + f] = f2bf(r[f * F + o]);
    }
}

// ---------------------------------------------------------------------------
// Counting sort of edges by DST -> perm + rowptr (R14-verified pipeline).
// ---------------------------------------------------------------------------
__global__ __launch_bounds__(256) void hist_kernel(
    const int* __restrict__ dst, int* __restrict__ cnt, int E)
{
    int e = blockIdx.x * blockDim.x + threadIdx.x;
    if (e < E) atomicAdd(&cnt[dst[e]], 1);
}

__global__ __launch_bounds__(256) void scan_partial(
    const int* __restrict__ cnt, int* __restrict__ partial, int N)
{
    const int i = blockIdx.x * 256 + threadIdx.x;
    int v = (i < N) ? cnt[i] : 0;
    #pragma unroll
    for (int off = 32; off > 0; off >>= 1) v += __shfl_down(v, off, 64);
    __shared__ int wsum[4];
    const int wave = threadIdx.x >> 6, lane = threadIdx.x & 63;
    if (lane == 0) wsum[wave] = v;
    __syncthreads();
    if (threadIdx.x == 0)
        partial[blockIdx.x] = wsum[0] + wsum[1] + wsum[2] + wsum[3];
}

__global__ void scan_top(int* __restrict__ partial, int M)
{
    const int t = threadIdx.x;
    int carry = 0;
    for (int base = 0; base < M; base += 64) {
        const int i = base + t;
        const int v0 = (i < M) ? partial[i] : 0;
        int v = v0;
        #pragma unroll
        for (int off = 1; off < 64; off <<= 1) {
            int u = __shfl_up(v, off, 64);
            if (t >= off) v += u;
        }
        if (i < M) partial[i] = carry + (v - v0);
        carry += __shfl(v, 63, 64);
    }
}

__global__ __launch_bounds__(256) void scan_final(
    const int* __restrict__ cnt, const int* __restrict__ partial,
    int* __restrict__ cursor, int* __restrict__ rowptr, int N)
{
    const int i = blockIdx.x * 256 + threadIdx.x;
    const int v0 = (i < N) ? cnt[i] : 0;
    int v = v0;
    const int wave = threadIdx.x >> 6, lane = threadIdx.x & 63;
    #pragma unroll
    for (int off = 1; off < 64; off <<= 1) {
        int u = __shfl_up(v, off, 64);
        if (lane >= off) v += u;
    }
    __shared__ int wsum[4];
    if (lane == 63) wsum[wave] = v;
    __syncthreads();
    int woff = 0;
    for (int ww = 0; ww < 4; ++ww) woff += (ww < wave) ? wsum[ww] : 0;
    if (i < N) {
        const int excl = partial[blockIdx.x] + woff + (v - v0);
        cursor[i] = excl;
        rowptr[i] = excl;
    }
}

__global__ __launch_bounds__(256) void scatter_kernel(
    const int* __restrict__ dst, int* __restrict__ cursor,
    int* __restrict__ perm, int E)
{
    int e = blockIdx.x * blockDim.x + threadIdx.x;
    if (e < E) {
        int p = atomicAdd(&cursor[dst[e]], 1);
        perm[p] = e;
    }
}

// esort: gather ef/src into dst-sorted slot order (R14-verified).
__global__ __launch_bounds__(256) void esort_kernel(
    const float* __restrict__ ef, const int* __restrict__ src,
    const int* __restrict__ perm,
    float* __restrict__ ef_s, int* __restrict__ src_s, int E)
{
    const int gid = blockIdx.x * blockDim.x + threadIdx.x;
    const int slot = gid >> 2;
    if (slot >= E) return;
    const int q = gid & 3;
    const int e = perm[slot];
    ((float4*)(ef_s + (size_t)slot * S))[q] = ((const float4*)(ef + (size_t)e * S))[q];
    if (q == 0) src_s[slot] = src[e];
}

// ---------------------------------------------------------------------------
// edge_msg v5: R14 body + 2-stage software pipeline over tiles — prefetch
// tile t+1's src/ef/x registers BEFORE computing tile t, so the dependent
// gather chain overlaps the ~700cy pack+MFMA block. Packed bf16 cvt
// (v_cvt_pk_bf16_f32) halves the pack-op count.
// ---------------------------------------------------------------------------
__global__ __launch_bounds__(256) void edge_msg(
    const float* __restrict__ xin,
    const float* __restrict__ ef_s,
    const int* __restrict__ src_s,
    const unsigned short* __restrict__ Wf,
    unsigned short* __restrict__ msg,
    int E)
{
    __shared__ v8s Wl[34 * 64];
    const int tid  = threadIdx.x;
    const int w    = tid >> 6;
    const int lane = tid & 63;
    const int lid  = lane & 15;
    const int quad = lane >> 4;

    {
        const uint4* s = (const uint4*)Wf;
        uint4* d = (uint4*)Wl;
        #pragma unroll
        for (int i = 0; i < 9; ++i) {
            const int idx = tid + 256 * i;
            if (idx < 2176) d[idx] = s[idx];
        }
    }
    __syncthreads();

    const int nTiles = (E + 15) >> 4;
    const int stride = gridDim.x * 4;
    int tile = blockIdx.x * 4 + w;
    if (tile >= nTiles) return;

    // prologue: load tile 0's data
    int  slot = tile * 16 + lid;
    bool live = (slot < E);
    int  s0   = live ? slot : 0;
    int  sn   = src_s[s0];
    const float4* xp = (const float4*)(xin + (size_t)sn * F + quad * 8);
    float4 xv0 = xp[0], xv1 = xp[1];
    const float4* efv = (const float4*)(ef_s + (size_t)s0 * S);
    float4 c0 = efv[0], c1 = efv[1], c2 = efv[2], c3 = efv[3];

    while (true) {
        const int nextTile = tile + stride;
        // prefetch next tile's chain (loads issue now, complete during compute)
        float4 nxv0, nxv1, nc0, nc1, nc2, nc3;
        bool nlive = false;
        if (nextTile < nTiles) {
            const int  ns_  = nextTile * 16 + lid;
            nlive = (ns_ < E);
            const int  ns0_ = nlive ? ns_ : 0;
            const int  nsn  = src_s[ns0_];
            const float4* nxp = (const float4*)(xin + (size_t)nsn * F + quad * 8);
            nxv0 = nxp[0]; nxv1 = nxp[1];
            const float4* nefv = (const float4*)(ef_s + (size_t)ns0_ * S);
            nc0 = nefv[0]; nc1 = nefv[1]; nc2 = nefv[2]; nc3 = nefv[3];
        }

        const float cs[S] = {c0.x, c0.y, c0.z, c0.w, c1.x, c1.y, c1.z, c1.w,
                             c2.x, c2.y, c2.z, c2.w, c3.x, c3.y, c3.z, c3.w};

        v4f acc0 = {0.f, 0.f, 0.f, 0.f};
        v4f acc1 = {0.f, 0.f, 0.f, 0.f};

        #pragma unroll
        for (int ck = 0; ck < S; ++ck) {
            const float sc = cs[ck];
            union { v8s s8; uint4 u4; } fr;
            fr.u4.x = pack2(sc * xv0.x, sc * xv0.y);
            fr.u4.y = pack2(sc * xv0.z, sc * xv0.w);
            fr.u4.z = pack2(sc * xv1.x, sc * xv1.y);
            fr.u4.w = pack2(sc * xv1.z, sc * xv1.w);
            acc0 = __builtin_amdgcn_mfma_f32_16x16x32_bf16(Wl[(2 * ck) * 64 + lane],     fr.s8, acc0, 0, 0, 0);
            acc1 = __builtin_amdgcn_mfma_f32_16x16x32_bf16(Wl[(2 * ck + 1) * 64 + lane], fr.s8, acc1, 0, 0, 0);
        }
        {
            union { v8s s8; uint4 u4; } fr;
            fr.u4.x = pack2(xv0.x, xv0.y);
            fr.u4.y = pack2(xv0.z, xv0.w);
            fr.u4.z = pack2(xv1.x, xv1.y);
            fr.u4.w = pack2(xv1.z, xv1.w);
            acc0 = __builtin_amdgcn_mfma_f32_16x16x32_bf16(Wl[32 * 64 + lane], fr.s8, acc0, 0, 0, 0);
            acc1 = __builtin_amdgcn_mfma_f32_16x16x32_bf16(Wl[33 * 64 + lane], fr.s8, acc1, 0, 0, 0);
        }

        if (live) {
            unsigned short* mp = msg + (size_t)slot * 32;
            uint2 p0, p1;
            p0.x = pack2(acc0[0], acc0[1]);
            p0.y = pack2(acc0[2], acc0[3]);
            p1.x = pack2(acc1[0], acc1[1]);
            p1.y = pack2(acc1[2], acc1[3]);
            *(uint2*)(mp + quad * 4)      = p0;
            *(uint2*)(mp + 16 + quad * 4) = p1;
        }

        if (nextTile >= nTiles) break;
        tile = nextTile;
        slot = tile * 16 + lid;
        live = nlive;
        xv0 = nxv0; xv1 = nxv1;
        c0 = nc0; c1 = nc1; c2 = nc2; c3 = nc3;
    }
}

// ---------------------------------------------------------------------------
// rootsum (R14-verified, unchanged).
// ---------------------------------------------------------------------------
__global__ __launch_bounds__(256) void rootsum(
    const float* __restrict__ in,
    const unsigned short* __restrict__ msg,
    const int* __restrict__ rowptr,
    const int* __restrict__ cnt,
    const unsigned short* __restrict__ Rt,
    const float* __restrict__ bias,
    float* __restrict__ h,
    int N)
{
    __shared__ float acc[64 * 33];
    __shared__ unsigned short As[64 * F];
    const int tid  = threadIdx.x;
    const int n0   = blockIdx.x * 64;
    const int w    = tid >> 6;
    const int lane = tid & 63;
    const int lid  = lane & 15;
    const int quad = lane >> 4;

    {
        const int nl = tid >> 2;
        const int kq = tid & 3;
        int n = n0 + nl; if (n > N - 1) n = N - 1;
        const float4* xp = (const float4*)(in + (size_t)n * F + kq * 8);
        float4 v0 = xp[0], v1 = xp[1];
        uint4 pk;
        pk.x = pack2(v0.x, v0.y);
        pk.y = pack2(v0.z, v0.w);
        pk.z = pack2(v1.x, v1.y);
        pk.w = pack2(v1.z, v1.w);
        const int slot = ((nl >> 4) * 4 + kq) * 16 + (nl & 15);
        *(uint4*)(As + slot * 8) = pk;
    }

    {
        const int nl = tid >> 2;
        const int oq = tid & 3;
        const int n  = n0 + nl;
        float a[8];
        #pragma unroll
        for (int j = 0; j < 8; ++j) a[j] = 0.f;
        if (n < N) {
            const int k0 = rowptr[n];
            const int k1 = k0 + cnt[n];
            for (int k = k0; k < k1; ++k) {
                const uint4 q = *(const uint4*)(msg + (size_t)k * 32 + oq * 8);
                a[0] += bf_lo(q.x); a[1] += bf_hi(q.x);
                a[2] += bf_lo(q.y); a[3] += bf_hi(q.y);
                a[4] += bf_lo(q.z); a[5] += bf_hi(q.z);
                a[6] += bf_lo(q.w); a[7] += bf_hi(q.w);
            }
        }
        float* ap = acc + nl * 33 + oq * 8;
        #pragma unroll
        for (int j = 0; j < 8; ++j) ap[j] = a[j];
    }
    __syncthreads();

    const int jt  = w & 1;
    const int ns0 = (w >> 1) * 2;
    const v8s rf = *(const v8s*)(Rt + (size_t)(jt * 16 + lid) * F + quad * 8);
    const int o0 = jt * 16 + quad * 4;
    const float4 bs = *(const float4*)(bias + o0);

    #pragma unroll
    for (int i = 0; i < 2; ++i) {
        const int ns = ns0 + i;
        const v8s af = *(const v8s*)(As + (((ns * 4 + quad) * 16) + lid) * 8);
        v4f d = {0.f, 0.f, 0.f, 0.f};
        d = __builtin_amdgcn_mfma_f32_16x16x32_bf16(rf, af, d, 0, 0, 0);
        const int n = n0 + ns * 16 + lid;
        if (n < N) {
            const float* ap = acc + (ns * 16 + lid) * 33 + o0;
            float4 hv;
            hv.x = fmaxf(d[0] + ap[0] + bs.x, 0.f);
            hv.y = fmaxf(d[1] + ap[1] + bs.y, 0.f);
            hv.z = fmaxf(d[2] + ap[2] + bs.z, 0.f);
            hv.w = fmaxf(d[3] + ap[3] + bs.w, 0.f);
            *(float4*)(h + (size_t)n * F + o0) = hv;
        }
    }
}

// ---------------------------------------------------------------------------
__global__ __launch_bounds__(256) void pool_kernel(
    const float* __restrict__ h, float* __restrict__ pooled, int N)
{
    const int c = threadIdx.x & (F - 1);
    float p = 0.0f;
    for (int n = blockIdx.x * 8 + (threadIdx.x >> 5); n < N; n += gridDim.x * 8)
        p += h[(size_t)n * F + c];
    __shared__ float red[256];
    red[threadIdx.x] = p;
    __syncthreads();
    for (int off = 128; off >= F; off >>= 1) {
        if (threadIdx.x < off) red[threadIdx.x] += red[threadIdx.x + off];
        __syncthreads();
    }
    if (threadIdx.x < F) atomicAdd(&pooled[threadIdx.x], red[threadIdx.x]);
}

__global__ void final_kernel(
    const float* __restrict__ pooled, const float* __restrict__ dw,
    const float* __restrict__ db, float* __restrict__ out)
{
    const int o = threadIdx.x;
    float v = (o < F) ? pooled[o] * dw[o] : 0.0f;
    #pragma unroll
    for (int off = 32; off > 0; off >>= 1) v += __shfl_down(v, off, 64);
    if (o == 0) out[0] = v + db[0];
}

// ---------------------------------------------------------------------------
// Last-resort fallback (tiny ws): round-1 implementation.
// ---------------------------------------------------------------------------
__global__ __launch_bounds__(256, 2) void ecc_edge_slow(
    const float* __restrict__ x, const float* __restrict__ ef,
    const int* __restrict__ src, const int* __restrict__ dst,
    const float* __restrict__ W, const float* __restrict__ B,
    float* __restrict__ agg, int E)
{
    const int tid = blockIdx.x * blockDim.x + threadIdx.x;
    const bool live = (tid < E);
    const int e = live ? tid : (E - 1);
    const int sn = src[e], dn = dst[e];
    float xr[F];
    const float4* xp = (const float4*)(x + (size_t)sn * F);
    #pragma unroll
    for (int i = 0; i < F / 4; ++i) {
        float4 v = xp[i];
        xr[4*i+0] = v.x; xr[4*i+1] = v.y; xr[4*i+2] = v.z; xr[4*i+3] = v.w;
    }
    float acc[F];
    #pragma unroll
    for (int o = 0; o < F; ++o) acc[o] = 0.0f;
    const float* erow = ef + (size_t)e * S;
    for (int s = 0; s < S; ++s) {
        const float es = erow[s];
        const float* Ws = W + s * (F * F);
        #pragma unroll
        for (int f = 0; f < F; ++f) {
            const float z = es * xr[f];
            #pragma unroll
            for (int o = 0; o < F; ++o) acc[o] = fmaf(z, Ws[f * F + o], acc[o]);
        }
    }
    #pragma unroll
    for (int f = 0; f < F; ++f) {
        const float xf = xr[f];
        #pragma unroll
        for (int o = 0; o < F; ++o) acc[o] = fmaf(xf, B[f * F + o], acc[o]);
    }
    if (live) {
        float* ap = agg + (size_t)dn * F;
        #pragma unroll
        for (int o = 0; o < F; ++o) atomicAdd(ap + o, acc[o]);
    }
}

__global__ __launch_bounds__(256) void ecc_node_slow(
    const float* __restrict__ xin, const float* __restrict__ root,
    const float* __restrict__ bias, float* __restrict__ h, int N)
{
    int t = blockIdx.x * blockDim.x + threadIdx.x;
    if (t >= N * F) return;
    const int n = t >> 5, o = t & (F - 1);
    const float* xrow = xin + (size_t)n * F;
    float v = h[t] + bias[o];
    #pragma unroll
    for (int f = 0; f < F; ++f) v = fmaf(xrow[f], root[f * F + o], v);
    h[t] = fmaxf(v, 0.0f);
}

// ---------------------------------------------------------------------------
extern "C" void kernel_launch(void* const* d_in, const int* in_sizes, int n_in,
                              void* d_out, int out_size, void* d_ws, size_t ws_size,
                              hipStream_t stream) {
    const float* x      = (const float*)d_in[0];
    const float* efeat  = (const float*)d_in[1];
    const int*   src    = (const int*)d_in[2];
    const int*   dst    = (const int*)d_in[3];
    const float* fgn_w1 = (const float*)d_in[4];
    const float* fgn_b1 = (const float*)d_in[5];
    const float* root1  = (const float*)d_in[6];
    const float* bias1  = (const float*)d_in[7];
    const float* fgn_w2 = (const float*)d_in[8];
    const float* fgn_b2 = (const float*)d_in[9];
    const float* root2  = (const float*)d_in[10];
    const float* bias2  = (const float*)d_in[11];
    const float* dense_w = (const float*)d_in[12];
    const float* dense_b = (const float*)d_in[13];

    const int N = in_sizes[0] / F;
    const int E = in_sizes[2];

    const int gridP = (N + 255) / 256;

    const size_t pooledB = 256;
    const size_t cntB    = align256((size_t)N * 4);
    const size_t rowB    = align256((size_t)N * 4);
    const size_t curB    = align256((size_t)N * 4);
    const size_t partB   = align256((size_t)gridP * 4);
    const size_t permB   = align256((size_t)E * 4);
    const size_t efsB    = align256((size_t)E * S * 4);
    const size_t srcsB   = align256((size_t)E * 4);
    const size_t msgB    = align256((size_t)E * 32 * 2);
    const size_t hB      = (size_t)N * F * 4;
    const size_t wfB     = align256((size_t)34 * 512 * 2);
    const size_t rtB     = align256((size_t)32 * 32 * 2);

    const size_t offCnt  = pooledB;
    const size_t offRow  = offCnt + cntB;
    const size_t offCur  = offRow + rowB;
    const size_t offPart = offCur + curB;
    const size_t offPerm = offPart + partB;
    const size_t offEfs  = offPerm + permB;
    const size_t offSrcs = offEfs + efsB;
    const size_t offMsg  = offSrcs + srcsB;
    const size_t offH1   = offMsg + msgB;
    const size_t offH2   = offH1 + hB;
    const size_t offW1   = offH2 + hB;
    const size_t offW2   = offW1 + wfB;
    const size_t offR1   = offW2 + wfB;
    const size_t offR2   = offR1 + rtB;
    const size_t need    = offR2 + rtB;

    const int eB         = (E + 255) / 256;
    const int nodeBlocks = (N * F + 255) / 256;

    if (ws_size >= need) {
        float* pooled = (float*)d_ws;
        int* cnt     = (int*)((char*)d_ws + offCnt);
        int* rowptr  = (int*)((char*)d_ws + offRow);
        int* cursor  = (int*)((char*)d_ws + offCur);
        int* partial = (int*)((char*)d_ws + offPart);
        int* perm    = (int*)((char*)d_ws + offPerm);
        float* ef_s  = (float*)((char*)d_ws + offEfs);
        int*   src_s = (int*)((char*)d_ws + offSrcs);
        unsigned short* msg = (unsigned short*)((char*)d_ws + offMsg);
        float* h1    = (float*)((char*)d_ws + offH1);
        float* h2    = (float*)((char*)d_ws + offH2);
        unsigned short* Wf1 = (unsigned short*)((char*)d_ws + offW1);
        unsigned short* Wf2 = (unsigned short*)((char*)d_ws + offW2);
        unsigned short* Rt1 = (unsigned short*)((char*)d_ws + offR1);
        unsigned short* Rt2 = (unsigned short*)((char*)d_ws + offR2);

        hipMemsetAsync(d_ws, 0, pooledB + cntB, stream);

        convert_w2<<<(2 * 18432 + 255) / 256, 256, 0, stream>>>(
            fgn_w1, fgn_b1, root1, fgn_w2, fgn_b2, root2, Wf1, Wf2, Rt1, Rt2);

        // CSR by dst + edge-data sort (once; reused by both layers)
        hist_kernel   <<<eB, 256, 0, stream>>>(dst, cnt, E);
        scan_partial  <<<gridP, 256, 0, stream>>>(cnt, partial, N);
        scan_top      <<<1, 64, 0, stream>>>(partial, gridP);
        scan_final    <<<gridP, 256, 0, stream>>>(cnt, partial, cursor, rowptr, N);
        scatter_kernel<<<eB, 256, 0, stream>>>(dst, cursor, perm, E);
        esort_kernel  <<<(E * 4 + 255) / 256, 256, 0, stream>>>(efeat, src, perm, ef_s, src_s, E);

        const int nTiles     = (E + 15) / 16;
        int edgeBlocks = (nTiles + 3) / 4;
        if (edgeBlocks > 1024) edgeBlocks = 1024;
        const int rsBlocks   = (N + 63) / 64;

        // ---- layer 1 ----
        edge_msg<<<edgeBlocks, 256, 0, stream>>>(x, ef_s, src_s, Wf1, msg, E);
        rootsum <<<rsBlocks, 256, 0, stream>>>(x, msg, rowptr, cnt, Rt1, bias1, h1, N);

        // ---- layer 2 ----
        edge_msg<<<edgeBlocks, 256, 0, stream>>>(h1, ef_s, src_s, Wf2, msg, E);
        rootsum <<<rsBlocks, 256, 0, stream>>>(h1, msg, rowptr, cnt, Rt2, bias2, h2, N);

        pool_kernel <<<512, 256, 0, stream>>>(h2, pooled, N);
        final_kernel<<<1, 64, 0, stream>>>(pooled, dense_w, dense_b, (float*)d_out);
    } else {
        float* agg1   = (float*)d_ws;
        float* agg2   = agg1 + (size_t)N * F;
        float* pooled = agg2 + (size_t)N * F;
        hipMemsetAsync(d_ws, 0, (2 * (size_t)N * F + F) * sizeof(float), stream);
        ecc_edge_slow<<<eB, 256, 0, stream>>>(x, efeat, src, dst, fgn_w1, fgn_b1, agg1, E);
        ecc_node_slow<<<nodeBlocks, 256, 0, stream>>>(x, root1, bias1, agg1, N);
        ecc_edge_slow<<<eB, 256, 0, stream>>>(agg1, efeat, src, dst, fgn_w2, fgn_b2, agg2, E);
        ecc_node_slow<<<nodeBlocks, 256, 0, stream>>>(agg1, root2, bias2, agg2, N);
        pool_kernel <<<512, 256, 0, stream>>>(agg2, pooled, N);
        final_kernel<<<1, 64, 0, stream>>>(pooled, dense_w, dense_b, (float*)d_out);
    }
}